// Round 9
// baseline (167.347 us; speedup 1.0000x reference)
//
#include <hip/hip_runtime.h>

typedef __attribute__((ext_vector_type(8))) short short8;
typedef __attribute__((ext_vector_type(4))) float f32x4;
typedef unsigned short u16;
typedef unsigned int u32;

#define NNODES 65536
#define FDIM 128
#define EPW 64          // edges per wave (before row-boundary trim)

__device__ __forceinline__ u16 f2bf(float f) {
    u32 u = __float_as_uint(f);
    u32 r = (u + 0x7fffu + ((u >> 16) & 1u)) >> 16;   // RNE
    return (u16)r;
}
__device__ __forceinline__ u32 pack2bf(float lo, float hi) {
    return ((u32)f2bf(hi) << 16) | f2bf(lo);
}

// ---------- fused prep: rowptr + wT casts + x cast, partitioned by blockIdx ----------
__global__ void prep_kernel(const int* __restrict__ erow, int* __restrict__ rowptr,
                            const float* __restrict__ w1, u16* __restrict__ wt1,
                            const float* __restrict__ w2, u16* __restrict__ wt2,
                            const float* __restrict__ w3, u16* __restrict__ wt3,
                            const float* __restrict__ x, u16* __restrict__ xb,
                            int n, int e) {
    const int b = blockIdx.x;
    const int tid = threadIdx.x;
    if (b < 257) {                               // rowptr
        int r = b * 256 + tid;
        if (r > n) return;
        int lo = 0, hi = e;
        while (lo < hi) {
            int mid = (lo + hi) >> 1;
            if (erow[mid] < r) lo = mid + 1; else hi = mid;
        }
        rowptr[r] = lo;
    } else if (b < 417) {                        // weight transpose-cast
        const float* w; u16* wt; int idx;
        if (b < 321)      { w = w1; wt = wt1; idx = (b - 257) * 256 + tid; }
        else if (b < 385) { w = w2; wt = wt2; idx = (b - 321) * 256 + tid; }
        else              { w = w3; wt = wt3; idx = (b - 385) * 256 + tid; }
        const int K = 128;
        const int NC = (b < 385) ? 128 : 64;
        if (idx >= K * NC) return;
        int nn = idx / K, k = idx - nn * K;
        wt[idx] = f2bf(w[k * NC + nn]);
    } else {                                     // x -> bf16 (uint2 per thread)
        int i = (b - 417) * 256 + tid;
        if (i >= n * FDIM / 4) return;
        float4 v = reinterpret_cast<const float4*>(x)[i];
        uint2 p;
        p.x = pack2bf(v.x, v.y);
        p.y = pack2bf(v.z, v.w);
        reinterpret_cast<uint2*>(xb)[i] = p;
    }
}

// ---------- SpMM v6: edge-centric, row-boundary-owned, lane = 2 features ----------
// Wave owns rows r with rowptr[r] in [e0,e1) (exact partition of sorted edges;
// no atomics). All 64 lanes process the same edge: gather = one coalesced 256B
// load, acc = 2 regs, row-change (uniform erow compare) = one coalesced 256B
// store. Ping-pong chunks of 8: next chunk's meta+gathers issue before current
// chunk's fmas (8 gathers in flight). No shuffles, no LDS.
// Tail blocks (>= eblocks) zero-fill deg-0 rows (~22) so ybuf is fully defined.
#define LOADGATHER(P, vv, rr, gg)                                              \
    {                                                                          \
        _Pragma("unroll")                                                      \
        for (int k = 0; k < 8; ++k) {                                          \
            int ek = (P) + k;                                                  \
            bool ok = ek < end;                                                \
            int c    = ok ? col[ek]  : 0;                                      \
            vv[k]    = ok ? val[ek]  : 0.f;                                    \
            rr[k]    = ok ? erow[ek] : -1;                                     \
            gg[k] = *reinterpret_cast<const u32*>(hl + (size_t)c * FDIM);      \
        }                                                                      \
    }

#define PROCESS(P, vv, rr, gg, rnext)                                          \
    {                                                                          \
        _Pragma("unroll")                                                      \
        for (int k = 0; k < 8; ++k) {                                          \
            int ek = (P) + k;                                                  \
            if (ek < end) {                                                    \
                a0 = fmaf(vv[k], __uint_as_float(gg[k] << 16), a0);            \
                a1 = fmaf(vv[k], __uint_as_float(gg[k] & 0xffff0000u), a1);    \
                int nx = (k < 7) ? rr[k + 1] : (rnext);                        \
                if (nx != rr[k]) {                                             \
                    *reinterpret_cast<u32*>(y + (size_t)rr[k] * FDIM           \
                                            + lane * 2) = pack2bf(a0, a1);     \
                    a0 = 0.f; a1 = 0.f;                                        \
                }                                                              \
            }                                                                  \
        }                                                                      \
    }

__global__ __launch_bounds__(256, 6)
void spmm_edge_kernel(const u16* __restrict__ h, const int* __restrict__ rowptr,
                      const int* __restrict__ erow, const int* __restrict__ col,
                      const float* __restrict__ val, u16* __restrict__ y,
                      int nE, int n, int eblocks) {
    if ((int)blockIdx.x >= eblocks) {            // zero-fill deg-0 rows
        int r = (blockIdx.x - eblocks) * 256 + threadIdx.x;
        if (r < n && rowptr[r] == rowptr[r + 1]) {
            uint4 z = {0u, 0u, 0u, 0u};
            u16* yr = y + (size_t)r * FDIM;
#pragma unroll
            for (int k = 0; k < 16; ++k)
                reinterpret_cast<uint4*>(yr)[k] = z;
        }
        return;
    }

    const int gw   = blockIdx.x * 4 + (threadIdx.x >> 6);
    const int lane = threadIdx.x & 63;
    const int e0 = gw * EPW;
    if (e0 >= nE) return;
    const int e1 = min(nE, e0 + EPW);

    const int rf = erow[e0];
    const int start = (rowptr[rf] == e0) ? e0 : rowptr[rf + 1];
    const int end   = rowptr[erow[e1 - 1] + 1];
    if (start >= end) return;

    const u16* hl = h + lane * 2;
    float a0 = 0.f, a1 = 0.f;

    float vA[8], vB[8]; int rA[8], rB[8]; u32 gA[8], gB[8];
    int e = start;
    LOADGATHER(e, vA, rA, gA);
    while (true) {
        LOADGATHER(e + 8, vB, rB, gB);
        PROCESS(e, vA, rA, gA, rB[0]);
        e += 8;
        if (e >= end) break;
        LOADGATHER(e + 8, vA, rA, gA);
        PROCESS(e, vB, rB, gB, rA[0]);
        e += 8;
        if (e >= end) break;
    }
}

// ---------- GEMM v3: LDS-staged weights, one 16-row chunk per wave ----------
template<int NT, bool RELU, bool OUT_BF16>
__global__ __launch_bounds__(256, 4)
void gemm_kernel(const u16* __restrict__ A, const u16* __restrict__ WT,
                 void* __restrict__ out, int M) {
    constexpr int NC = NT * 16;
    constexpr int LSTR = 136;                 // u16: 128 data + 8 pad
    __shared__ u16 wlds[NC * LSTR];

    const int t = threadIdx.x;
    const int fr = t & 15;
#pragma unroll
    for (int n = t >> 4; n < NC; n += 16)
        *reinterpret_cast<uint4*>(&wlds[n * LSTR + fr * 8]) =
            *reinterpret_cast<const uint4*>(&WT[(size_t)n * 128 + fr * 8]);
    __syncthreads();

    const int lane = t & 63;
    const int dn = lane & 15;
    const int kg = lane >> 4;
    const int r0 = (blockIdx.x * 4 + (t >> 6)) << 4;
    if (r0 >= M) return;

    f32x4 acc[NT];
#pragma unroll
    for (int nt = 0; nt < NT; ++nt) acc[nt] = (f32x4){0.f, 0.f, 0.f, 0.f};

#pragma unroll
    for (int s = 0; s < 4; ++s) {
        short8 a = *reinterpret_cast<const short8*>(
            &A[(size_t)(r0 + dn) * 128 + s * 32 + kg * 8]);
#pragma unroll
        for (int nt = 0; nt < NT; ++nt) {
            short8 b = *reinterpret_cast<const short8*>(
                &wlds[(nt * 16 + dn) * LSTR + s * 32 + kg * 8]);
            acc[nt] = __builtin_amdgcn_mfma_f32_16x16x32_bf16(b, a, acc[nt], 0, 0, 0);
        }
    }

    const int row = r0 + dn;
#pragma unroll
    for (int nt = 0; nt < NT; ++nt) {
        float v0 = acc[nt][0], v1 = acc[nt][1], v2 = acc[nt][2], v3 = acc[nt][3];
        if (RELU) {
            v0 = fmaxf(v0, 0.f); v1 = fmaxf(v1, 0.f);
            v2 = fmaxf(v2, 0.f); v3 = fmaxf(v3, 0.f);
        }
        if (OUT_BF16) {
            uint2 p; p.x = pack2bf(v0, v1); p.y = pack2bf(v2, v3);
            *reinterpret_cast<uint2*>(
                (u16*)out + (size_t)row * NC + nt * 16 + kg * 4) = p;
        } else {
            float4 p = make_float4(v0, v1, v2, v3);
            *reinterpret_cast<float4*>(
                (float*)out + (size_t)row * NC + nt * 16 + kg * 4) = p;
        }
    }
}

// ---------- Fused GEMM2+GEMM3: out = relu(Y @ W2) @ W3, no h2 round-trip ----------
__global__ __launch_bounds__(256, 2)
void gemm23_kernel(const u16* __restrict__ A, const u16* __restrict__ WT2,
                   const u16* __restrict__ WT3, float* __restrict__ out, int M) {
    constexpr int LSTR = 136;
    __shared__ u16 w2l[128 * LSTR];           // 34816 B
    __shared__ u16 h2l[4][16 * LSTR];         // 17408 B (4.3KB per wave, private)

    const int t = threadIdx.x;
    const int fr = t & 15;
#pragma unroll
    for (int n = t >> 4; n < 128; n += 16)
        *reinterpret_cast<uint4*>(&w2l[n * LSTR + fr * 8]) =
            *reinterpret_cast<const uint4*>(&WT2[(size_t)n * 128 + fr * 8]);

    const int wave = t >> 6;
    const int lane = t & 63;
    const int dn = lane & 15;
    const int kg = lane >> 4;

    short8 bw3[4][4];
#pragma unroll
    for (int nt = 0; nt < 4; ++nt)
#pragma unroll
        for (int s = 0; s < 4; ++s)
            bw3[nt][s] = *reinterpret_cast<const short8*>(
                &WT3[(size_t)(nt * 16 + dn) * 128 + s * 32 + kg * 8]);

    __syncthreads();

    const int r0 = (blockIdx.x * 4 + wave) << 4;
    if (r0 >= M) return;

    f32x4 acc2[8];
#pragma unroll
    for (int nt = 0; nt < 8; ++nt) acc2[nt] = (f32x4){0.f, 0.f, 0.f, 0.f};
#pragma unroll
    for (int s = 0; s < 4; ++s) {
        short8 a = *reinterpret_cast<const short8*>(
            &A[(size_t)(r0 + dn) * 128 + s * 32 + kg * 8]);
#pragma unroll
        for (int nt = 0; nt < 8; ++nt) {
            short8 b = *reinterpret_cast<const short8*>(
                &w2l[(nt * 16 + dn) * LSTR + s * 32 + kg * 8]);
            acc2[nt] = __builtin_amdgcn_mfma_f32_16x16x32_bf16(b, a, acc2[nt], 0, 0, 0);
        }
    }

    u16* my = h2l[wave];
#pragma unroll
    for (int nt = 0; nt < 8; ++nt) {
        float v0 = fmaxf(acc2[nt][0], 0.f), v1 = fmaxf(acc2[nt][1], 0.f);
        float v2 = fmaxf(acc2[nt][2], 0.f), v3 = fmaxf(acc2[nt][3], 0.f);
        uint2 p; p.x = pack2bf(v0, v1); p.y = pack2bf(v2, v3);
        *reinterpret_cast<uint2*>(&my[dn * LSTR + nt * 16 + kg * 4]) = p;
    }

    f32x4 acc3[4];
#pragma unroll
    for (int nt = 0; nt < 4; ++nt) acc3[nt] = (f32x4){0.f, 0.f, 0.f, 0.f};
#pragma unroll
    for (int s = 0; s < 4; ++s) {
        short8 a = *reinterpret_cast<const short8*>(
            &my[dn * LSTR + s * 32 + kg * 8]);
#pragma unroll
        for (int nt = 0; nt < 4; ++nt)
            acc3[nt] = __builtin_amdgcn_mfma_f32_16x16x32_bf16(bw3[nt][s], a, acc3[nt], 0, 0, 0);
    }

    const int row = r0 + dn;
#pragma unroll
    for (int nt = 0; nt < 4; ++nt)
        *reinterpret_cast<float4*>(out + (size_t)row * 64 + nt * 16 + kg * 4) =
            make_float4(acc3[nt][0], acc3[nt][1], acc3[nt][2], acc3[nt][3]);
}

extern "C" void kernel_launch(void* const* d_in, const int* in_sizes, int n_in,
                              void* d_out, int out_size, void* d_ws, size_t ws_size,
                              hipStream_t stream) {
    const float* x    = (const float*)d_in[0];
    const float* w1   = (const float*)d_in[1];
    const float* w2   = (const float*)d_in[2];
    const float* w3   = (const float*)d_in[3];
    const int*   erow = (const int*)d_in[4];
    const int*   ecol = (const int*)d_in[5];
    const float* eval = (const float*)d_in[6];
    float* out = (float*)d_out;

    const int N = in_sizes[0] / FDIM;
    const int E = in_sizes[4];

    char* ws = (char*)d_ws;
    int* rowptr = (int*)ws;                                  // (N+1)*4
    u16* wt1 = (u16*)(ws + (512 << 10));                     // 32KB
    u16* wt2 = wt1 + 128 * 128;                              // 32KB
    u16* wt3 = wt2 + 128 * 128;                              // 16KB
    u16* ybuf = (u16*)(ws + (1 << 20));                      // 16MB bf16 [N][128]
    u16* hbuf = (u16*)(ws + (18u << 20));                    // 16MB bf16 [N][128]

    const int xblocks = N * FDIM / 4 / 256;                  // 8192
    prep_kernel<<<417 + xblocks, 256, 0, stream>>>(erow, rowptr, w1, wt1, w2, wt2,
                                                   w3, wt3, x, hbuf, N, E);

    const int eblocks = (E + EPW * 4 - 1) / (EPW * 4);       // 2048
    const int zblocks = (N + 255) / 256;                     // 256
    spmm_edge_kernel<<<eblocks + zblocks, 256, 0, stream>>>(
        hbuf, rowptr, erow, ecol, eval, ybuf, E, N, eblocks);
    gemm_kernel<8, true, true><<<N / 64, 256, 0, stream>>>(ybuf, wt1, hbuf, N);
    spmm_edge_kernel<<<eblocks + zblocks, 256, 0, stream>>>(
        hbuf, rowptr, erow, ecol, eval, ybuf, E, N, eblocks);
    gemm23_kernel<<<N / 64, 256, 0, stream>>>(ybuf, wt2, wt3, out, N);
}

// Round 10
// 96.205 us; speedup vs baseline: 1.7395x; 1.7395x over previous
//
#include <hip/hip_runtime.h>

typedef __attribute__((ext_vector_type(8))) short short8;
typedef __attribute__((ext_vector_type(4))) float f32x4;
typedef unsigned short u16;
typedef unsigned int u32;

#define NNODES 65536
#define FDIM 128

__device__ __forceinline__ u16 f2bf(float f) {
    u32 u = __float_as_uint(f);
    u32 r = (u + 0x7fffu + ((u >> 16) & 1u)) >> 16;   // RNE
    return (u16)r;
}
__device__ __forceinline__ u32 pack2bf(float lo, float hi) {
    return ((u32)f2bf(hi) << 16) | f2bf(lo);
}
__device__ __forceinline__ float bf2f(short s) {
    return __uint_as_float(((u32)(u16)s) << 16);
}

// ---------- fused prep: rowptr + wT casts + x cast, partitioned by blockIdx ----------
__global__ void prep_kernel(const int* __restrict__ erow, int* __restrict__ rowptr,
                            const float* __restrict__ w1, u16* __restrict__ wt1,
                            const float* __restrict__ w2, u16* __restrict__ wt2,
                            const float* __restrict__ w3, u16* __restrict__ wt3,
                            const float* __restrict__ x, u16* __restrict__ xb,
                            int n, int e) {
    const int b = blockIdx.x;
    const int tid = threadIdx.x;
    if (b < 257) {                               // rowptr
        int r = b * 256 + tid;
        if (r > n) return;
        int lo = 0, hi = e;
        while (lo < hi) {
            int mid = (lo + hi) >> 1;
            if (erow[mid] < r) lo = mid + 1; else hi = mid;
        }
        rowptr[r] = lo;
    } else if (b < 417) {                        // weight transpose-cast
        const float* w; u16* wt; int idx;
        if (b < 321)      { w = w1; wt = wt1; idx = (b - 257) * 256 + tid; }
        else if (b < 385) { w = w2; wt = wt2; idx = (b - 321) * 256 + tid; }
        else              { w = w3; wt = wt3; idx = (b - 385) * 256 + tid; }
        const int K = 128;
        const int NC = (b < 385) ? 128 : 64;
        if (idx >= K * NC) return;
        int nn = idx / K, k = idx - nn * K;
        wt[idx] = f2bf(w[k * NC + nn]);
    } else {                                     // x -> bf16 (uint2 per thread)
        int i = (b - 417) * 256 + tid;
        if (i >= n * FDIM / 4) return;
        float4 v = reinterpret_cast<const float4*>(x)[i];
        uint2 p;
        p.x = pack2bf(v.x, v.y);
        p.y = pack2bf(v.z, v.w);
        reinterpret_cast<uint2*>(xb)[i] = p;
    }
}

// ---------- Fused SpMM + GEMM(s), 16 rows per block ----------
// SpMM phase = R7's measured-best structure (2 rows/wave, 4-slot butterfly, 4
// gathers in flight, deep meta prefetch), run twice per wave -> 16-row tile in
// LDS (stride 136: conflict-free). Same waves/CU and in-flight gathers as the
// standalone spmm, so gather speed is preserved; ybuf round-trip eliminated.
// GEMM phase: swapped-operand MFMA against register-held weight frags (L2-hot
// loads after the barrier; 2 col-tiles per wave). LAYER==2 chains
// gemm2 -> relu -> LDS -> gemm3 (w3) -> fp32 out in the same block.
template<int LAYER>
__global__ __launch_bounds__(256, 6)
void fused_kernel(const u16* __restrict__ h, const int* __restrict__ rowptr,
                  const int* __restrict__ col, const float* __restrict__ val,
                  const u16* __restrict__ WA, const u16* __restrict__ WB,
                  void* __restrict__ outp, int n) {
    constexpr int LSTR = 136;                    // u16 stride: 128 data + 8 pad
    __shared__ u16 ytile[16 * LSTR];             // spmm result tile (bf16)
    __shared__ u16 h2tile[16 * LSTR];            // layer-2 intermediate

    const int t = threadIdx.x;
    const int wave = t >> 6;
    const int lane = t & 63;
    const int slot = lane >> 4;
    const int fg = lane & 15;
    const int R0 = blockIdx.x * 16;
    const u16* hf = h + fg * 8;

    // ================= SpMM phase =================
    for (int it = 0; it < 2; ++it) {
        const int rA = R0 + wave * 4 + it * 2;
        const int sA = rowptr[rA], eA = rowptr[rA + 1], eB = rowptr[rA + 2];

        int iA = sA + slot;
        int c0A = 0, c1A = 0; float v0A = 0.f, v1A = 0.f;
        if (iA < eA)     { c0A = col[iA];     v0A = val[iA]; }
        if (iA + 4 < eA) { c1A = col[iA + 4]; v1A = val[iA + 4]; }
        int iB = eA + slot;
        int c0B = 0, c1B = 0; float v0B = 0.f, v1B = 0.f;
        if (iB < eB)     { c0B = col[iB];     v0B = val[iB]; }
        if (iB + 4 < eB) { c1B = col[iB + 4]; v1B = val[iB + 4]; }

        short8 g0A = *reinterpret_cast<const short8*>(hf + (size_t)c0A * FDIM);
        short8 g1A = *reinterpret_cast<const short8*>(hf + (size_t)c1A * FDIM);
        short8 g0B = *reinterpret_cast<const short8*>(hf + (size_t)c0B * FDIM);
        short8 g1B = *reinterpret_cast<const short8*>(hf + (size_t)c1B * FDIM);

        int jA = iA + 8;
        int c2A = 0, c3A = 0; float v2A = 0.f, v3A = 0.f;
        if (jA < eA)     { c2A = col[jA];     v2A = val[jA]; }
        if (jA + 4 < eA) { c3A = col[jA + 4]; v3A = val[jA + 4]; }
        int jB = iB + 8;
        int c2B = 0, c3B = 0; float v2B = 0.f, v3B = 0.f;
        if (jB < eB)     { c2B = col[jB];     v2B = val[jB]; }
        if (jB + 4 < eB) { c3B = col[jB + 4]; v3B = val[jB + 4]; }

        float accA[8], accB[8];
#pragma unroll
        for (int j = 0; j < 8; ++j) { accA[j] = 0.f; accB[j] = 0.f; }

#pragma unroll
        for (int j = 0; j < 8; ++j) accA[j] = fmaf(v0A, bf2f(g0A[j]), accA[j]);
#pragma unroll
        for (int j = 0; j < 8; ++j) accA[j] = fmaf(v1A, bf2f(g1A[j]), accA[j]);
#pragma unroll
        for (int j = 0; j < 8; ++j) accB[j] = fmaf(v0B, bf2f(g0B[j]), accB[j]);
#pragma unroll
        for (int j = 0; j < 8; ++j) accB[j] = fmaf(v1B, bf2f(g1B[j]), accB[j]);

        while (jA < eA) {
            short8 g0 = *reinterpret_cast<const short8*>(hf + (size_t)c2A * FDIM);
            short8 g1 = *reinterpret_cast<const short8*>(hf + (size_t)c3A * FDIM);
            float v0 = v2A, v1 = v3A;
            jA += 8;
            c2A = 0; c3A = 0; v2A = 0.f; v3A = 0.f;
            if (jA < eA)     { c2A = col[jA];     v2A = val[jA]; }
            if (jA + 4 < eA) { c3A = col[jA + 4]; v3A = val[jA + 4]; }
#pragma unroll
            for (int j = 0; j < 8; ++j) accA[j] = fmaf(v0, bf2f(g0[j]), accA[j]);
#pragma unroll
            for (int j = 0; j < 8; ++j) accA[j] = fmaf(v1, bf2f(g1[j]), accA[j]);
        }
        while (jB < eB) {
            short8 g0 = *reinterpret_cast<const short8*>(hf + (size_t)c2B * FDIM);
            short8 g1 = *reinterpret_cast<const short8*>(hf + (size_t)c3B * FDIM);
            float v0 = v2B, v1 = v3B;
            jB += 8;
            c2B = 0; c3B = 0; v2B = 0.f; v3B = 0.f;
            if (jB < eB)     { c2B = col[jB];     v2B = val[jB]; }
            if (jB + 4 < eB) { c3B = col[jB + 4]; v3B = val[jB + 4]; }
#pragma unroll
            for (int j = 0; j < 8; ++j) accB[j] = fmaf(v0, bf2f(g0[j]), accB[j]);
#pragma unroll
            for (int j = 0; j < 8; ++j) accB[j] = fmaf(v1, bf2f(g1[j]), accB[j]);
        }

#pragma unroll
        for (int m = 16; m <= 32; m <<= 1) {
#pragma unroll
            for (int j = 0; j < 8; ++j) {
                accA[j] += __shfl_xor(accA[j], m, 64);
                accB[j] += __shfl_xor(accB[j], m, 64);
            }
        }

        float a0 = 0.f, a1 = 0.f, b0 = 0.f, b1 = 0.f;
#pragma unroll
        for (int ss = 0; ss < 4; ++ss)
            if (slot == ss) {
                a0 = accA[ss * 2]; a1 = accA[ss * 2 + 1];
                b0 = accB[ss * 2]; b1 = accB[ss * 2 + 1];
            }
        const int rloc = wave * 4 + it * 2;
        *reinterpret_cast<u32*>(&ytile[rloc * LSTR + fg * 8 + slot * 2]) = pack2bf(a0, a1);
        *reinterpret_cast<u32*>(&ytile[(rloc + 1) * LSTR + fg * 8 + slot * 2]) = pack2bf(b0, b1);
    }
    __syncthreads();

    // ================= GEMM phase =================
    const int dn = lane & 15;
    const int kg = lane >> 4;

    // gemm vs WA (w1 or w2): wave handles col-tiles nt = 2*wave, 2*wave+1
    short8 bw[2][4];
#pragma unroll
    for (int q = 0; q < 2; ++q)
#pragma unroll
        for (int s = 0; s < 4; ++s)
            bw[q][s] = *reinterpret_cast<const short8*>(
                &WA[(size_t)((2 * wave + q) * 16 + dn) * 128 + s * 32 + kg * 8]);

    f32x4 acc[2];
    acc[0] = (f32x4){0.f, 0.f, 0.f, 0.f};
    acc[1] = (f32x4){0.f, 0.f, 0.f, 0.f};
#pragma unroll
    for (int s = 0; s < 4; ++s) {
        short8 a = *reinterpret_cast<const short8*>(&ytile[dn * LSTR + s * 32 + kg * 8]);
        acc[0] = __builtin_amdgcn_mfma_f32_16x16x32_bf16(bw[0][s], a, acc[0], 0, 0, 0);
        acc[1] = __builtin_amdgcn_mfma_f32_16x16x32_bf16(bw[1][s], a, acc[1], 0, 0, 0);
    }

    if (LAYER == 1) {
        u16* o = (u16*)outp;
#pragma unroll
        for (int q = 0; q < 2; ++q) {
            float v0 = fmaxf(acc[q][0], 0.f), v1 = fmaxf(acc[q][1], 0.f);
            float v2 = fmaxf(acc[q][2], 0.f), v3 = fmaxf(acc[q][3], 0.f);
            uint2 p; p.x = pack2bf(v0, v1); p.y = pack2bf(v2, v3);
            *reinterpret_cast<uint2*>(
                &o[(size_t)(R0 + dn) * 128 + (2 * wave + q) * 16 + kg * 4]) = p;
        }
    } else {
        // relu -> h2 tile in LDS
#pragma unroll
        for (int q = 0; q < 2; ++q) {
            float v0 = fmaxf(acc[q][0], 0.f), v1 = fmaxf(acc[q][1], 0.f);
            float v2 = fmaxf(acc[q][2], 0.f), v3 = fmaxf(acc[q][3], 0.f);
            uint2 p; p.x = pack2bf(v0, v1); p.y = pack2bf(v2, v3);
            *reinterpret_cast<uint2*>(
                &h2tile[dn * LSTR + (2 * wave + q) * 16 + kg * 4]) = p;
        }
        __syncthreads();

        // gemm3 vs WB (w3): wave handles col-tile nt3 = wave (out cols 16*wave..+15)
        short8 bw3[4];
#pragma unroll
        for (int s = 0; s < 4; ++s)
            bw3[s] = *reinterpret_cast<const short8*>(
                &WB[(size_t)(wave * 16 + dn) * 128 + s * 32 + kg * 8]);

        f32x4 acc3 = (f32x4){0.f, 0.f, 0.f, 0.f};
#pragma unroll
        for (int s = 0; s < 4; ++s) {
            short8 a = *reinterpret_cast<const short8*>(&h2tile[dn * LSTR + s * 32 + kg * 8]);
            acc3 = __builtin_amdgcn_mfma_f32_16x16x32_bf16(bw3[s], a, acc3, 0, 0, 0);
        }
        float* o = (float*)outp;
        *reinterpret_cast<float4*>(&o[(size_t)(R0 + dn) * 64 + wave * 16 + kg * 4]) =
            make_float4(acc3[0], acc3[1], acc3[2], acc3[3]);
    }
}

extern "C" void kernel_launch(void* const* d_in, const int* in_sizes, int n_in,
                              void* d_out, int out_size, void* d_ws, size_t ws_size,
                              hipStream_t stream) {
    const float* x    = (const float*)d_in[0];
    const float* w1   = (const float*)d_in[1];
    const float* w2   = (const float*)d_in[2];
    const float* w3   = (const float*)d_in[3];
    const int*   erow = (const int*)d_in[4];
    const int*   ecol = (const int*)d_in[5];
    const float* eval = (const float*)d_in[6];
    float* out = (float*)d_out;

    const int N = in_sizes[0] / FDIM;
    const int E = in_sizes[4];

    char* ws = (char*)d_ws;
    int* rowptr = (int*)ws;                                  // (N+1)*4
    u16* wt1 = (u16*)(ws + (512 << 10));                     // 32KB
    u16* wt2 = wt1 + 128 * 128;                              // 32KB
    u16* wt3 = wt2 + 128 * 128;                              // 16KB
    u16* xbuf = (u16*)(ws + (1 << 20));                      // 16MB bf16 [N][128]
    u16* hbuf = (u16*)(ws + (18u << 20));                    // 16MB bf16 [N][128]

    const int xblocks = N * FDIM / 4 / 256;                  // 8192
    prep_kernel<<<417 + xblocks, 256, 0, stream>>>(erow, rowptr, w1, wt1, w2, wt2,
                                                   w3, wt3, x, xbuf, N, E);
    // layer 1: h1 = relu(spmm(x) @ w1)
    fused_kernel<1><<<N / 16, 256, 0, stream>>>(xbuf, rowptr, ecol, eval,
                                                wt1, wt1, hbuf, N);
    // layer 2+3: out = relu(spmm(h1) @ w2) @ w3
    fused_kernel<2><<<N / 16, 256, 0, stream>>>(hbuf, rowptr, ecol, eval,
                                                wt2, wt3, (void*)out, N);
}